// Round 19
// baseline (292.822 us; speedup 1.0000x reference)
//
#include <hip/hip_runtime.h>
#include <math.h>

#define MID 512
#define NB  65536
#define G   4096
#define NBLK 258
#define PTS  4128   // 258 blocks * 16 points; table point p holds x = (p-1)/G

struct NetP { const float *w1,*b1,*w2,*b2,*w3,*b3; };
struct AllP { NetP n[3]; float* table; };

// ---------------------------------------------------------------------------
// Kernel 0a: transpose W2 (512x512) -> W2T[k][n] per net.
// ---------------------------------------------------------------------------
__global__ __launch_bounds__(256)
void k_prep(AllP P, float* __restrict__ w2t)
{
    __shared__ float t[32][33];
    const int net = blockIdx.z;
    const float* src = (net == 0) ? P.n[0].w2 : (net == 1) ? P.n[1].w2 : P.n[2].w2;
    float* dst = w2t + (size_t)net * MID * MID;
    const int bx = blockIdx.x * 32, by = blockIdx.y * 32;
    const int tx = threadIdx.x & 31, ty = threadIdx.x >> 5;   // ty 0..7
    #pragma unroll
    for (int j = 0; j < 4; ++j)
        t[ty + 8 * j][tx] = src[(size_t)(by + ty + 8 * j) * MID + bx + tx];
    __syncthreads();
    #pragma unroll
    for (int j = 0; j < 4; ++j)
        dst[(size_t)(bx + ty + 8 * j) * MID + by + tx] = t[tx][ty + 8 * j];
}

// ---------------------------------------------------------------------------
// Kernel 0b: precompute h1 = sin(sin(4*(x*w1+b1))) in slab order:
// h1t[net][blk][k*16+m], 8192 floats (32KB) per (net,blk).
// ---------------------------------------------------------------------------
__global__ __launch_bounds__(256)
void k_h1(AllP P, float* __restrict__ h1t)
{
    const int net = blockIdx.y;
    const NetP np = (net == 0) ? P.n[0] : (net == 1) ? P.n[1] : P.n[2];
    const int blk = blockIdx.x;
    float* dst = h1t + ((size_t)net * NBLK + blk) * 8192;
    const float invG = 1.0f / (float)G;
    #pragma unroll 4
    for (int j = 0; j < 32; ++j) {
        const int idx = threadIdx.x + j * 256;    // = k*16 + m
        const int k = idx >> 4, m = idx & 15;
        const float xv = ((float)(blk * 16 + m) - 1.0f) * invG;
        const float z = 4.f * fmaf(xv, np.w1[k], np.b1[k]);
        dst[idx] = sinf(sinf(z));
    }
}

// ---------------------------------------------------------------------------
// Kernel 1: fused SIREN, 256 threads x 16 points/block, 774 blocks (3.02/CU).
// R18 found every shape keeps h-reads on the single per-CU LDS pipe (~288
// cyc/k vs 192 FMA cyc/k -> 1.5x oversubscribed, VALUBusy pinned ~51%).
// FIX: h is WAVE-UNIFORM per k -> read it from global through a pointer that
// depends only on blockIdx and k; the compiler selects s_load into SGPRs
// (scalar pipe, only 12 loads/k/CU) and v_fma takes the SGPR operand
// directly. The k-loop now has ZERO LDS instructions: 1 global b64 (W) +
// 1 uniform 64B scalar load + 32 FMAs per thread per k.
// Tile: P=16 x C=2 (32 acc floats). LDS used only for layer 3 (R18 verbatim).
// ---------------------------------------------------------------------------
__global__ __attribute__((amdgpu_waves_per_eu(2, 8))) __launch_bounds__(256)
void k_siren(AllP P, const float* __restrict__ w2t, const float* __restrict__ h1t)
{
    __shared__ float sbuf[MID * 16];    // 32 KB: layer-3 h2 buffer only

    const int tid = threadIdx.x;
    const int net = blockIdx.y;
    const int m0  = blockIdx.x * 16;
    NetP np;
    if (net == 0)      np = P.n[0];
    else if (net == 1) np = P.n[1];
    else               np = P.n[2];
    const float* wslab = w2t + (size_t)net * MID * MID;
    const float* hb    = h1t + ((size_t)net * NBLK + blockIdx.x) * 8192;  // uniform

    const int c  = tid & 63;
    const int w  = tid >> 6;          // wave 0..3 -> col quarter
    const int cw = w * 128 + c * 2;   // first of this thread's 2 cols

#define ACC_DECL(i) float2 a##i = make_float2(0.f, 0.f);
    ACC_DECL(0)  ACC_DECL(1)  ACC_DECL(2)  ACC_DECL(3)
    ACC_DECL(4)  ACC_DECL(5)  ACC_DECL(6)  ACC_DECL(7)
    ACC_DECL(8)  ACC_DECL(9)  ACC_DECL(10) ACC_DECL(11)
    ACC_DECL(12) ACC_DECL(13) ACC_DECL(14) ACC_DECL(15)

#define FMA2(i, hv) \
        a##i.x = fmaf(hv, wa.x, a##i.x); a##i.y = fmaf(hv, wa.y, a##i.y);

    // ---- K loop: barrier-free, LDS-free. W per-lane b64; h uniform (SGPR).
    {
        const float* wp = wslab + cw;
        #pragma unroll 4
        for (int k = 0; k < MID; ++k) {
            const float2 wa = *reinterpret_cast<const float2*>(wp + (size_t)k * MID);
            const float4 hA = *reinterpret_cast<const float4*>(hb + k * 16 + 0);
            const float4 hB = *reinterpret_cast<const float4*>(hb + k * 16 + 4);
            const float4 hC = *reinterpret_cast<const float4*>(hb + k * 16 + 8);
            const float4 hD = *reinterpret_cast<const float4*>(hb + k * 16 + 12);
            FMA2(0,  hA.x) FMA2(1,  hA.y) FMA2(2,  hA.z) FMA2(3,  hA.w)
            FMA2(4,  hB.x) FMA2(5,  hB.y) FMA2(6,  hB.z) FMA2(7,  hB.w)
            FMA2(8,  hC.x) FMA2(9,  hC.y) FMA2(10, hC.z) FMA2(11, hC.w)
            FMA2(12, hD.x) FMA2(13, hD.y) FMA2(14, hD.z) FMA2(15, hD.w)
        }
    }

    {   // epilogue: h2 = sin(sin(4*(z + b2))) — this thread's 2 cols, 16 pts
        const float2 bv = *reinterpret_cast<const float2*>(np.b2 + cw);
#define SS1(v, b) v = sinf(sinf(4.f * ((v) + (b))));
#define SSROW(i) SS1(a##i.x, bv.x) SS1(a##i.y, bv.y)
        SSROW(0)  SSROW(1)  SSROW(2)  SSROW(3)
        SSROW(4)  SSROW(5)  SSROW(6)  SSROW(7)
        SSROW(8)  SSROW(9)  SSROW(10) SSROW(11)
        SSROW(12) SSROW(13) SSROW(14) SSROW(15)
    }

    // layer 3 (R18 verbatim): float2 stores with XOR key 2*row; since
    // 2qq ^ 2m = 2(qq^m), the float4 READ pattern is R16's proven
    // conflict-free sbuf[m*512 + ((qq^m)&127)*4].
    {
        const int n2 = w * 64 + c;   // logical float2 col index 0..255
#define L3ST(i) \
        *reinterpret_cast<float2*>(&sbuf[(i) * 512 + ((n2 ^ (2 * (i))) & 255) * 2]) = a##i;
        L3ST(0)  L3ST(1)  L3ST(2)  L3ST(3)
        L3ST(4)  L3ST(5)  L3ST(6)  L3ST(7)
        L3ST(8)  L3ST(9)  L3ST(10) L3ST(11)
        L3ST(12) L3ST(13) L3ST(14) L3ST(15)
    }
    __syncthreads();

    {   // m = tid&15 (point), jg = tid>>4 (0..15) -> output cols jg*2, jg*2+1
        const int m  = tid & 15;
        const int jg = tid >> 4;
        const float* wr0 = np.w3 + (size_t)(jg * 2) * MID;
        const float* wr1 = wr0 + MID;
        float p0a = 0.f, p0b = 0.f, p1a = 0.f, p1b = 0.f;
        #pragma unroll 8
        for (int qq = 0; qq < 128; ++qq) {
            const float4 h  = *reinterpret_cast<const float4*>(
                &sbuf[m * 512 + ((qq ^ m) & 127) * 4]);
            const float4 w0 = *reinterpret_cast<const float4*>(wr0 + qq * 4);
            const float4 w1 = *reinterpret_cast<const float4*>(wr1 + qq * 4);
            p0a = fmaf(h.y, w0.y, fmaf(h.x, w0.x, p0a));
            p0b = fmaf(h.w, w0.w, fmaf(h.z, w0.z, p0b));
            p1a = fmaf(h.y, w1.y, fmaf(h.x, w1.x, p1a));
            p1b = fmaf(h.w, w1.w, fmaf(h.z, w1.z, p1b));
        }
        const float2 b3v = *reinterpret_cast<const float2*>(np.b3 + jg * 2);
        float2 r; r.x = p0a + p0b + b3v.x; r.y = p1a + p1b + b3v.y;
        *reinterpret_cast<float2*>(
            &P.table[((size_t)net * PTS + (m0 + m)) * 32 + jg * 2]) = r;
    }
}

// ---------------------------------------------------------------------------
// Kernel 2: Catmull-Rom interp + Tucker contraction — ROUND-6 VERSION VERBATIM
// (measured ~93us. R12 s_load variant ~145us; R7/R10 2-sample spilled.
// Do not touch.)
// ---------------------------------------------------------------------------
#define F4MA(acc, s, rp, k) { const float4 _v = (rp)[k]; \
    acc.x = fmaf((s), _v.x, acc.x); acc.y = fmaf((s), _v.y, acc.y); \
    acc.z = fmaf((s), _v.z, acc.z); acc.w = fmaf((s), _v.w, acc.w); }

#define GROW8(Pfx, w, rp, off) \
    F4MA(Pfx##0,(w),rp,(off)+0) F4MA(Pfx##1,(w),rp,(off)+1) \
    F4MA(Pfx##2,(w),rp,(off)+2) F4MA(Pfx##3,(w),rp,(off)+3) \
    F4MA(Pfx##4,(w),rp,(off)+4) F4MA(Pfx##5,(w),rp,(off)+5) \
    F4MA(Pfx##6,(w),rp,(off)+6) F4MA(Pfx##7,(w),rp,(off)+7)

// Catmull-Rom setup: x*G is EXACT in fp32 (power-of-two scale).
#define CRSETUP(x_, iv, c0, c1, c2, c3) \
    int iv; float c0, c1, c2, c3; { \
        float xx = (x_) * (float)G; \
        int i = (int)xx; i = i < 0 ? 0 : (i > G - 1 ? G - 1 : i); iv = i; \
        float t = xx - (float)i; \
        float t2 = t * t, t3 = t2 * t; \
        c0 = fmaf(-0.5f, t3, t2) - 0.5f * t; \
        c1 = fmaf(1.5f, t3, fmaf(-2.5f, t2, 1.f)); \
        c2 = fmaf(-1.5f, t3, fmaf(2.f, t2, 0.5f * t)); \
        c3 = 0.5f * (t3 - t2); }

__global__ __attribute__((amdgpu_waves_per_eu(2, 4))) __launch_bounds__(256)
void k_ic(const float* __restrict__ table, const float* __restrict__ core,
          const float* __restrict__ x, float* __restrict__ out)
{
    __shared__ float cs[8 * 1024];   // 32 KB: 8 r-rows of C per round
    __shared__ float red[256];

    const int tid = threadIdx.x;
    const int ls  = tid & 63;        // local sample
    const int rh  = tid >> 6;        // 0..3, wave-uniform; r = rb*8+rh*2+{0,1}
    const int g   = blockIdx.x * 64 + ls;

    const float xu = x[(size_t)g * 3 + 0];
    const float xv = x[(size_t)g * 3 + 1];
    const float xw = x[(size_t)g * 3 + 2];

#define DECLZ(Pn) float4 Pn = make_float4(0.f,0.f,0.f,0.f);
    DECLZ(W0) DECLZ(W1) DECLZ(W2) DECLZ(W3) DECLZ(W4) DECLZ(W5) DECLZ(W6) DECLZ(W7)
    DECLZ(V0) DECLZ(V1) DECLZ(V2) DECLZ(V3) DECLZ(V4) DECLZ(V5) DECLZ(V6) DECLZ(V7)
    float2 U0, U1, U2, U3;

    {   // W net (index 2)
        CRSETUP(xw, iw, c0, c1, c2, c3)
        const float4* rp = reinterpret_cast<const float4*>(
            table + ((size_t)2 * PTS + iw) * 32);
        GROW8(W, c0, rp, 0) GROW8(W, c1, rp, 8) GROW8(W, c2, rp, 16) GROW8(W, c3, rp, 24)
    }
    {   // V net (index 1)
        CRSETUP(xv, iv2, c0, c1, c2, c3)
        const float4* rp = reinterpret_cast<const float4*>(
            table + ((size_t)1 * PTS + iv2) * 32);
        GROW8(V, c0, rp, 0) GROW8(V, c1, rp, 8) GROW8(V, c2, rp, 16) GROW8(V, c3, rp, 24)
    }
    {   // U net (index 0): this thread's 8 r-cols = rb*8 + rh*2 + {0,1}
        CRSETUP(xu, iu, c0, c1, c2, c3)
        const float2* up = reinterpret_cast<const float2*>(table + (size_t)iu * 32);
#define UROW(rbv, dst) { \
        const float2 t0 = up[0 * 16 + (rbv) * 4 + rh]; \
        const float2 t1 = up[1 * 16 + (rbv) * 4 + rh]; \
        const float2 t2 = up[2 * 16 + (rbv) * 4 + rh]; \
        const float2 t3 = up[3 * 16 + (rbv) * 4 + rh]; \
        dst.x = fmaf(c0,t0.x,fmaf(c1,t1.x,fmaf(c2,t2.x,c3*t3.x))); \
        dst.y = fmaf(c0,t0.y,fmaf(c1,t1.y,fmaf(c2,t2.y,c3*t3.y))); }
        UROW(0, U0) UROW(1, U1) UROW(2, U2) UROW(3, U3)
    }

#define TQC(rl, s, tq, Wv) { \
    const float4 c4 = *reinterpret_cast<const float4*>( \
        &cs[(rh * 2 + (rl)) * 1024 + (s) * 32 + (tq) * 4]); \
    aa = fmaf(Wv.w, c4.w, fmaf(Wv.z, c4.z, fmaf(Wv.y, c4.y, fmaf(Wv.x, c4.x, aa)))); }

#define SONE(rl, s, vcomp) { float aa = 0.f; \
    TQC(rl, s, 0, W0) TQC(rl, s, 1, W1) TQC(rl, s, 2, W2) TQC(rl, s, 3, W3) \
    TQC(rl, s, 4, W4) TQC(rl, s, 5, W5) TQC(rl, s, 6, W6) TQC(rl, s, 7, W7) \
    tracc = fmaf(vcomp, aa, tracc); }

#define SG(rl, sb, Vv) \
    SONE(rl, 4*(sb)+0, Vv.x) SONE(rl, 4*(sb)+1, Vv.y) \
    SONE(rl, 4*(sb)+2, Vv.z) SONE(rl, 4*(sb)+3, Vv.w)

#define RL1(rl, ucomp) { float tracc = 0.f; \
    SG(rl, 0, V0) SG(rl, 1, V1) SG(rl, 2, V2) SG(rl, 3, V3) \
    SG(rl, 4, V4) SG(rl, 5, V5) SG(rl, 6, V6) SG(rl, 7, V7) \
    o = fmaf(ucomp, tracc, o); }

#define RBLOCK(rb) { \
    __syncthreads(); \
    _Pragma("unroll") \
    for (int cc = 0; cc < 8; ++cc) \
        *reinterpret_cast<float4*>(&cs[cc * 1024 + tid * 4]) = \
            *reinterpret_cast<const float4*>(core + (size_t)((rb) * 8 + cc) * 1024 + tid * 4); \
    __syncthreads(); \
    RL1(0, U##rb.x) RL1(1, U##rb.y) }

    float o = 0.f;
    RBLOCK(0) RBLOCK(1) RBLOCK(2) RBLOCK(3)

    red[tid] = o;
    __syncthreads();
    if (tid < 64)
        out[blockIdx.x * 64 + tid] =
            red[tid] + red[tid + 64] + red[tid + 128] + red[tid + 192];
}

// ---------------------------------------------------------------------------
extern "C" void kernel_launch(void* const* d_in, const int* in_sizes, int n_in,
                              void* d_out, int out_size, void* d_ws, size_t ws_size,
                              hipStream_t stream)
{
    AllP P;
    for (int net = 0; net < 3; ++net) {
        const int b = 1 + net * 6;
        P.n[net].w1 = (const float*)d_in[b + 0];
        P.n[net].b1 = (const float*)d_in[b + 1];
        P.n[net].w2 = (const float*)d_in[b + 2];
        P.n[net].b2 = (const float*)d_in[b + 3];
        P.n[net].w3 = (const float*)d_in[b + 4];
        P.n[net].b3 = (const float*)d_in[b + 5];
    }
    const float* xin  = (const float*)d_in[0];
    const float* core = (const float*)d_in[19];
    float* wsf   = (float*)d_ws;
    float* table = wsf;                            // 3*4128*32   = 1.58 MB
    float* w2t   = wsf + (size_t)3 * PTS * 32;     // 3*512*512   = 3.00 MB
    float* h1t   = w2t + (size_t)3 * MID * MID;    // 3*258*8192  = 25.4 MB
    P.table = table;

    k_prep <<<dim3(16, 16, 3), 256, 0, stream>>>(P, w2t);
    k_h1   <<<dim3(NBLK, 3), 256, 0, stream>>>(P, h1t);
    k_siren<<<dim3(NBLK, 3), 256, 0, stream>>>(P, w2t, h1t);
    k_ic   <<<NB / 64, 256, 0, stream>>>(table, core, xin, (float*)d_out);
}

// Round 20
// 287.996 us; speedup vs baseline: 1.0168x; 1.0168x over previous
//
#include <hip/hip_runtime.h>
#include <math.h>

#define MID 512
#define NB  65536
#define G   4096
#define NBLK 258
#define PTS  4128   // 258 blocks * 16 points; table point p holds x = (p-1)/G

struct NetP { const float *w1,*b1,*w2,*b2,*w3,*b3; };
struct AllP { NetP n[3]; float* table; };

// ---------------------------------------------------------------------------
// Kernel 0: transpose W2 (512x512) -> W2T[k][n] per net.
// ---------------------------------------------------------------------------
__global__ __launch_bounds__(256)
void k_prep(AllP P, float* __restrict__ w2t)
{
    __shared__ float t[32][33];
    const int net = blockIdx.z;
    const float* src = (net == 0) ? P.n[0].w2 : (net == 1) ? P.n[1].w2 : P.n[2].w2;
    float* dst = w2t + (size_t)net * MID * MID;
    const int bx = blockIdx.x * 32, by = blockIdx.y * 32;
    const int tx = threadIdx.x & 31, ty = threadIdx.x >> 5;   // ty 0..7
    #pragma unroll
    for (int j = 0; j < 4; ++j)
        t[ty + 8 * j][tx] = src[(size_t)(by + ty + 8 * j) * MID + bx + tx];
    __syncthreads();
    #pragma unroll
    for (int j = 0; j < 4; ++j)
        dst[(size_t)(bx + ty + 8 * j) * MID + by + tx] = t[tx][ty + 8 * j];
}

// ---------------------------------------------------------------------------
// Kernel 1: fused SIREN, 256 threads x 16 points/block, 774 blocks (3.02/CU).
// R16/R18/R19 triangulation: halving W-bytes = flat, doubling h-LDS-reads =
// flat, scalar-h = flat -> k_siren is LATENCY-bound (810 cyc/k/CU measured vs
// ~192 cyc/k FMA issue; compiler drains vmcnt per unroll batch).
// FIX: explicit 2-stage register pipeline on the W stream. Batches A (k..k+3)
// and B (k+4..k+7) in named float2 regs; loop steps 8 k: compute(A), issue
// A<-k+8, compute(B), issue B<-k+12 -> each load is in flight for one full
// 4-k compute block (~256 issue cyc) + 3 waves/SIMD cover the rest of the
// ~300cy L2 latency. Static alternation (no runtime-indexed arrays).
// Tile P=16 x C=2 (32 acc floats); h in LDS (4 broadcast b128/k, proven).
// waves_per_eu(2,4): 128-reg budget for acc32 + Wbuf16 + h-frags (~100 live).
// ---------------------------------------------------------------------------
__global__ __attribute__((amdgpu_waves_per_eu(2, 4))) __launch_bounds__(256)
void k_siren(AllP P, const float* __restrict__ w2t)
{
    __shared__ float sbuf[MID * 16];    // 32 KB: h1 [k][m] during loop; h2 after

    const int tid = threadIdx.x;
    const int net = blockIdx.y;
    const int m0  = blockIdx.x * 16;
    NetP np;
    if (net == 0)      np = P.n[0];
    else if (net == 1) np = P.n[1];
    else               np = P.n[2];
    const float* wslab = w2t + (size_t)net * MID * MID;

    const int c  = tid & 63;
    const int w  = tid >> 6;          // wave 0..3 -> col quarter
    const int cw = w * 128 + c * 2;   // first of this thread's 2 cols

    // ---- fill h1[k][m] = sin(sin(4*(x_m*w1[k]+b1[k]))), 32 entries/thread
    {
        const float invG = 1.0f / (float)G;
        for (int j = 0; j < 32; ++j) {
            const int idx = tid + j * 256;        // = k*16 + m
            const int k = idx >> 4, m = idx & 15;
            const float xv = ((float)(m0 + m) - 1.0f) * invG;
            const float z = 4.f * fmaf(xv, np.w1[k], np.b1[k]);
            sbuf[idx] = sinf(sinf(z));
        }
    }
    __syncthreads();

#define ACC_DECL(i) float2 a##i = make_float2(0.f, 0.f);
    ACC_DECL(0)  ACC_DECL(1)  ACC_DECL(2)  ACC_DECL(3)
    ACC_DECL(4)  ACC_DECL(5)  ACC_DECL(6)  ACC_DECL(7)
    ACC_DECL(8)  ACC_DECL(9)  ACC_DECL(10) ACC_DECL(11)
    ACC_DECL(12) ACC_DECL(13) ACC_DECL(14) ACC_DECL(15)

#define FMA2(i, hv, wv) \
        a##i.x = fmaf(hv, wv.x, a##i.x); a##i.y = fmaf(hv, wv.y, a##i.y);

    // one k-step: 4 broadcast h-reads + 32 FMAs against W batch register wv
#define COMP1(wv, kk) { \
        const float4 hA = *reinterpret_cast<const float4*>(&sbuf[(kk) * 16 + 0]); \
        const float4 hB = *reinterpret_cast<const float4*>(&sbuf[(kk) * 16 + 4]); \
        const float4 hC = *reinterpret_cast<const float4*>(&sbuf[(kk) * 16 + 8]); \
        const float4 hD = *reinterpret_cast<const float4*>(&sbuf[(kk) * 16 + 12]); \
        FMA2(0,  hA.x, wv) FMA2(1,  hA.y, wv) FMA2(2,  hA.z, wv) FMA2(3,  hA.w, wv) \
        FMA2(4,  hB.x, wv) FMA2(5,  hB.y, wv) FMA2(6,  hB.z, wv) FMA2(7,  hB.w, wv) \
        FMA2(8,  hC.x, wv) FMA2(9,  hC.y, wv) FMA2(10, hC.z, wv) FMA2(11, hC.w, wv) \
        FMA2(12, hD.x, wv) FMA2(13, hD.y, wv) FMA2(14, hD.z, wv) FMA2(15, hD.w, wv) }

#define LDW(dst, kk) dst = *reinterpret_cast<const float2*>(wp + (size_t)(kk) * MID);

    {
        const float* wp = wslab + cw;
        float2 wA0, wA1, wA2, wA3, wB0, wB1, wB2, wB3;
        LDW(wA0, 0) LDW(wA1, 1) LDW(wA2, 2) LDW(wA3, 3)
        LDW(wB0, 4) LDW(wB1, 5) LDW(wB2, 6) LDW(wB3, 7)
        for (int kb = 0; kb < MID; kb += 8) {
            // compute batch A (k = kb .. kb+3)
            COMP1(wA0, kb + 0) COMP1(wA1, kb + 1)
            COMP1(wA2, kb + 2) COMP1(wA3, kb + 3)
            if (kb + 8 < MID) {   // refill A for kb+8..kb+11
                LDW(wA0, kb + 8)  LDW(wA1, kb + 9)
                LDW(wA2, kb + 10) LDW(wA3, kb + 11)
            }
            // compute batch B (k = kb+4 .. kb+7)
            COMP1(wB0, kb + 4) COMP1(wB1, kb + 5)
            COMP1(wB2, kb + 6) COMP1(wB3, kb + 7)
            if (kb + 12 < MID) {  // refill B for kb+12..kb+15
                LDW(wB0, kb + 12) LDW(wB1, kb + 13)
                LDW(wB2, kb + 14) LDW(wB3, kb + 15)
            }
        }
    }
    __syncthreads();   // h1 no longer needed; sbuf becomes the h2 buffer

    {   // epilogue: h2 = sin(sin(4*(z + b2))) — this thread's 2 cols, 16 pts
        const float2 bv = *reinterpret_cast<const float2*>(np.b2 + cw);
#define SS1(v, b) v = sinf(sinf(4.f * ((v) + (b))));
#define SSROW(i) SS1(a##i.x, bv.x) SS1(a##i.y, bv.y)
        SSROW(0)  SSROW(1)  SSROW(2)  SSROW(3)
        SSROW(4)  SSROW(5)  SSROW(6)  SSROW(7)
        SSROW(8)  SSROW(9)  SSROW(10) SSROW(11)
        SSROW(12) SSROW(13) SSROW(14) SSROW(15)
    }

    // layer 3 (R18 verbatim): float2 stores with XOR key 2*row; since
    // 2qq ^ 2m = 2(qq^m), the float4 READ pattern is R16's proven
    // conflict-free sbuf[m*512 + ((qq^m)&127)*4].
    {
        const int n2 = w * 64 + c;   // logical float2 col index 0..255
#define L3ST(i) \
        *reinterpret_cast<float2*>(&sbuf[(i) * 512 + ((n2 ^ (2 * (i))) & 255) * 2]) = a##i;
        L3ST(0)  L3ST(1)  L3ST(2)  L3ST(3)
        L3ST(4)  L3ST(5)  L3ST(6)  L3ST(7)
        L3ST(8)  L3ST(9)  L3ST(10) L3ST(11)
        L3ST(12) L3ST(13) L3ST(14) L3ST(15)
    }
    __syncthreads();

    {   // m = tid&15 (point), jg = tid>>4 (0..15) -> output cols jg*2, jg*2+1
        const int m  = tid & 15;
        const int jg = tid >> 4;
        const float* wr0 = np.w3 + (size_t)(jg * 2) * MID;
        const float* wr1 = wr0 + MID;
        float p0a = 0.f, p0b = 0.f, p1a = 0.f, p1b = 0.f;
        #pragma unroll 8
        for (int qq = 0; qq < 128; ++qq) {
            const float4 h  = *reinterpret_cast<const float4*>(
                &sbuf[m * 512 + ((qq ^ m) & 127) * 4]);
            const float4 w0 = *reinterpret_cast<const float4*>(wr0 + qq * 4);
            const float4 w1 = *reinterpret_cast<const float4*>(wr1 + qq * 4);
            p0a = fmaf(h.y, w0.y, fmaf(h.x, w0.x, p0a));
            p0b = fmaf(h.w, w0.w, fmaf(h.z, w0.z, p0b));
            p1a = fmaf(h.y, w1.y, fmaf(h.x, w1.x, p1a));
            p1b = fmaf(h.w, w1.w, fmaf(h.z, w1.z, p1b));
        }
        const float2 b3v = *reinterpret_cast<const float2*>(np.b3 + jg * 2);
        float2 r; r.x = p0a + p0b + b3v.x; r.y = p1a + p1b + b3v.y;
        *reinterpret_cast<float2*>(
            &P.table[((size_t)net * PTS + (m0 + m)) * 32 + jg * 2]) = r;
    }
}

// ---------------------------------------------------------------------------
// Kernel 2: Catmull-Rom interp + Tucker contraction — ROUND-6 VERSION VERBATIM
// (measured ~93us. R12 s_load variant ~145us; R7/R10 2-sample spilled.
// Do not touch.)
// ---------------------------------------------------------------------------
#define F4MA(acc, s, rp, k) { const float4 _v = (rp)[k]; \
    acc.x = fmaf((s), _v.x, acc.x); acc.y = fmaf((s), _v.y, acc.y); \
    acc.z = fmaf((s), _v.z, acc.z); acc.w = fmaf((s), _v.w, acc.w); }

#define GROW8(Pfx, w, rp, off) \
    F4MA(Pfx##0,(w),rp,(off)+0) F4MA(Pfx##1,(w),rp,(off)+1) \
    F4MA(Pfx##2,(w),rp,(off)+2) F4MA(Pfx##3,(w),rp,(off)+3) \
    F4MA(Pfx##4,(w),rp,(off)+4) F4MA(Pfx##5,(w),rp,(off)+5) \
    F4MA(Pfx##6,(w),rp,(off)+6) F4MA(Pfx##7,(w),rp,(off)+7)

// Catmull-Rom setup: x*G is EXACT in fp32 (power-of-two scale).
#define CRSETUP(x_, iv, c0, c1, c2, c3) \
    int iv; float c0, c1, c2, c3; { \
        float xx = (x_) * (float)G; \
        int i = (int)xx; i = i < 0 ? 0 : (i > G - 1 ? G - 1 : i); iv = i; \
        float t = xx - (float)i; \
        float t2 = t * t, t3 = t2 * t; \
        c0 = fmaf(-0.5f, t3, t2) - 0.5f * t; \
        c1 = fmaf(1.5f, t3, fmaf(-2.5f, t2, 1.f)); \
        c2 = fmaf(-1.5f, t3, fmaf(2.f, t2, 0.5f * t)); \
        c3 = 0.5f * (t3 - t2); }

__global__ __attribute__((amdgpu_waves_per_eu(2, 4))) __launch_bounds__(256)
void k_ic(const float* __restrict__ table, const float* __restrict__ core,
          const float* __restrict__ x, float* __restrict__ out)
{
    __shared__ float cs[8 * 1024];   // 32 KB: 8 r-rows of C per round
    __shared__ float red[256];

    const int tid = threadIdx.x;
    const int ls  = tid & 63;        // local sample
    const int rh  = tid >> 6;        // 0..3, wave-uniform; r = rb*8+rh*2+{0,1}
    const int g   = blockIdx.x * 64 + ls;

    const float xu = x[(size_t)g * 3 + 0];
    const float xv = x[(size_t)g * 3 + 1];
    const float xw = x[(size_t)g * 3 + 2];

#define DECLZ(Pn) float4 Pn = make_float4(0.f,0.f,0.f,0.f);
    DECLZ(W0) DECLZ(W1) DECLZ(W2) DECLZ(W3) DECLZ(W4) DECLZ(W5) DECLZ(W6) DECLZ(W7)
    DECLZ(V0) DECLZ(V1) DECLZ(V2) DECLZ(V3) DECLZ(V4) DECLZ(V5) DECLZ(V6) DECLZ(V7)
    float2 U0, U1, U2, U3;

    {   // W net (index 2)
        CRSETUP(xw, iw, c0, c1, c2, c3)
        const float4* rp = reinterpret_cast<const float4*>(
            table + ((size_t)2 * PTS + iw) * 32);
        GROW8(W, c0, rp, 0) GROW8(W, c1, rp, 8) GROW8(W, c2, rp, 16) GROW8(W, c3, rp, 24)
    }
    {   // V net (index 1)
        CRSETUP(xv, iv2, c0, c1, c2, c3)
        const float4* rp = reinterpret_cast<const float4*>(
            table + ((size_t)1 * PTS + iv2) * 32);
        GROW8(V, c0, rp, 0) GROW8(V, c1, rp, 8) GROW8(V, c2, rp, 16) GROW8(V, c3, rp, 24)
    }
    {   // U net (index 0): this thread's 8 r-cols = rb*8 + rh*2 + {0,1}
        CRSETUP(xu, iu, c0, c1, c2, c3)
        const float2* up = reinterpret_cast<const float2*>(table + (size_t)iu * 32);
#define UROW(rbv, dst) { \
        const float2 t0 = up[0 * 16 + (rbv) * 4 + rh]; \
        const float2 t1 = up[1 * 16 + (rbv) * 4 + rh]; \
        const float2 t2 = up[2 * 16 + (rbv) * 4 + rh]; \
        const float2 t3 = up[3 * 16 + (rbv) * 4 + rh]; \
        dst.x = fmaf(c0,t0.x,fmaf(c1,t1.x,fmaf(c2,t2.x,c3*t3.x))); \
        dst.y = fmaf(c0,t0.y,fmaf(c1,t1.y,fmaf(c2,t2.y,c3*t3.y))); }
        UROW(0, U0) UROW(1, U1) UROW(2, U2) UROW(3, U3)
    }

#define TQC(rl, s, tq, Wv) { \
    const float4 c4 = *reinterpret_cast<const float4*>( \
        &cs[(rh * 2 + (rl)) * 1024 + (s) * 32 + (tq) * 4]); \
    aa = fmaf(Wv.w, c4.w, fmaf(Wv.z, c4.z, fmaf(Wv.y, c4.y, fmaf(Wv.x, c4.x, aa)))); }

#define SONE(rl, s, vcomp) { float aa = 0.f; \
    TQC(rl, s, 0, W0) TQC(rl, s, 1, W1) TQC(rl, s, 2, W2) TQC(rl, s, 3, W3) \
    TQC(rl, s, 4, W4) TQC(rl, s, 5, W5) TQC(rl, s, 6, W6) TQC(rl, s, 7, W7) \
    tracc = fmaf(vcomp, aa, tracc); }

#define SG(rl, sb, Vv) \
    SONE(rl, 4*(sb)+0, Vv.x) SONE(rl, 4*(sb)+1, Vv.y) \
    SONE(rl, 4*(sb)+2, Vv.z) SONE(rl, 4*(sb)+3, Vv.w)

#define RL1(rl, ucomp) { float tracc = 0.f; \
    SG(rl, 0, V0) SG(rl, 1, V1) SG(rl, 2, V2) SG(rl, 3, V3) \
    SG(rl, 4, V4) SG(rl, 5, V5) SG(rl, 6, V6) SG(rl, 7, V7) \
    o = fmaf(ucomp, tracc, o); }

#define RBLOCK(rb) { \
    __syncthreads(); \
    _Pragma("unroll") \
    for (int cc = 0; cc < 8; ++cc) \
        *reinterpret_cast<float4*>(&cs[cc * 1024 + tid * 4]) = \
            *reinterpret_cast<const float4*>(core + (size_t)((rb) * 8 + cc) * 1024 + tid * 4); \
    __syncthreads(); \
    RL1(0, U##rb.x) RL1(1, U##rb.y) }

    float o = 0.f;
    RBLOCK(0) RBLOCK(1) RBLOCK(2) RBLOCK(3)

    red[tid] = o;
    __syncthreads();
    if (tid < 64)
        out[blockIdx.x * 64 + tid] =
            red[tid] + red[tid + 64] + red[tid + 128] + red[tid + 192];
}

// ---------------------------------------------------------------------------
extern "C" void kernel_launch(void* const* d_in, const int* in_sizes, int n_in,
                              void* d_out, int out_size, void* d_ws, size_t ws_size,
                              hipStream_t stream)
{
    AllP P;
    for (int net = 0; net < 3; ++net) {
        const int b = 1 + net * 6;
        P.n[net].w1 = (const float*)d_in[b + 0];
        P.n[net].b1 = (const float*)d_in[b + 1];
        P.n[net].w2 = (const float*)d_in[b + 2];
        P.n[net].b2 = (const float*)d_in[b + 3];
        P.n[net].w3 = (const float*)d_in[b + 4];
        P.n[net].b3 = (const float*)d_in[b + 5];
    }
    const float* xin  = (const float*)d_in[0];
    const float* core = (const float*)d_in[19];
    float* wsf   = (float*)d_ws;
    float* table = wsf;                            // 3*4128*32 = 1.58 MB
    float* w2t   = wsf + (size_t)3 * PTS * 32;     // 3*512*512 = 3.00 MB
    P.table = table;

    k_prep <<<dim3(16, 16, 3), 256, 0, stream>>>(P, w2t);
    k_siren<<<dim3(NBLK, 3), 256, 0, stream>>>(P, w2t);
    k_ic   <<<NB / 64, 256, 0, stream>>>(table, core, xin, (float*)d_out);
}